// Round 1
// baseline (506.819 us; speedup 1.0000x reference)
//
#include <hip/hip_runtime.h>
#include <math.h>

// Single-head equivalence: all NUM_HEADS=4 heads see identical q,k,v and
// scalar scale/bias -> per-head outputs identical -> mean over heads is
// identity. Compute one head + double Lorentz normalization.

#define NQ 4096
#define DD 129
#define BM 16        // query rows per block
#define BN 64        // KV rows per tile
#define NT 256       // threads per block
#define KST 132      // LDS stride for K tile (16B-aligned rows)
#define QST 132      // LDS stride for Q tile
#define PST 65       // LDS stride for P tile (odd -> conflict-free b32)

__global__ __launch_bounds__(NT) void hyper_attn_kernel(
    const float* __restrict__ Qg, const float* __restrict__ Kg,
    const float* __restrict__ scale_p, const float* __restrict__ bias_p,
    float* __restrict__ outg)
{
  __shared__ float Ks[BN * KST];          // 33792 B
  __shared__ float Qs[BM * QST];          // 8448 B  (reused as AveS in epilogue)
  __shared__ float Ps[BM * PST];          // 4160 B
  __shared__ float mrunS[BM], lrunS[BM], alphaS[BM], A128[BM];

  const int tid  = threadIdx.x;
  const int row0 = blockIdx.x * BM;

  const float scale     = scale_p[0];
  const float bias      = bias_p[0];
  const float inv_scale = 1.0f / scale;

  // ---- stage Q (negate Lorentz time coord d=0), zero pads ----
  for (int i = tid; i < BM * DD; i += NT) {
    int r = i / DD, c = i - r * DD;
    float v = Qg[(row0 + r) * DD + c];
    Qs[r * QST + c] = (c == 0) ? -v : v;
  }
  if (tid < BM) {
    Qs[tid * QST + 129] = 0.f; Qs[tid * QST + 130] = 0.f; Qs[tid * QST + 131] = 0.f;
    mrunS[tid] = -INFINITY; lrunS[tid] = 0.f; A128[tid] = 0.f;
  }
  if (tid < BN) {  // K-tile pad cols stay zero across all tiles
    Ks[tid * KST + 129] = 0.f; Ks[tid * KST + 130] = 0.f; Ks[tid * KST + 131] = 0.f;
  }

  // S-phase / PV-phase thread mapping
  const int rg   = tid >> 5;          // 0..7
  const int cg   = tid & 31;          // 0..31
  const int rowA = rg * 2, rowB = rg * 2 + 1;

  float acc0[4] = {0.f, 0.f, 0.f, 0.f};   // rowA, cols 4cg..4cg+3
  float acc1[4] = {0.f, 0.f, 0.f, 0.f};   // rowB

  for (int t = 0; t < NQ / BN; ++t) {
    __syncthreads();   // previous tile's PV done; K tile reusable

    // ---- stage K tile: linear float4 global reads (coalesced, aligned) ----
    {
      const float4* src = (const float4*)(Kg + (size_t)t * BN * DD);  // BN*DD*4 = 33024 B, 16B-mult
      for (int i4 = tid; i4 < (BN * DD) / 4; i4 += NT) {
        float4 v = src[i4];
        int g = i4 * 4;
        int r = g / DD;
        int c = g - r * DD;
        float vals[4] = {v.x, v.y, v.z, v.w};
#pragma unroll
        for (int e = 0; e < 4; ++e) {
          Ks[r * KST + c] = vals[e];
          ++c;
          if (c == DD) { c = 0; ++r; }
        }
      }
    }
    __syncthreads();

    // ---- S = (2 + 2*qm.k)/scale + bias, 2x2 per thread ----
    {
      float d00 = 0.f, d01 = 0.f, d10 = 0.f, d11 = 0.f;
      const float4* qa4 = (const float4*)(Qs + rowA * QST);
      const float4* qb4 = (const float4*)(Qs + rowB * QST);
      const float4* k04 = (const float4*)(Ks + cg * KST);
      const float4* k14 = (const float4*)(Ks + (cg + 32) * KST);
#pragma unroll 4
      for (int q = 0; q < 33; ++q) {        // 33 quads = 132 cols (pads are zero)
        float4 qa = qa4[q], qb = qb4[q], k0 = k04[q], k1 = k14[q];
        d00 += qa.x * k0.x; d00 += qa.y * k0.y; d00 += qa.z * k0.z; d00 += qa.w * k0.w;
        d01 += qa.x * k1.x; d01 += qa.y * k1.y; d01 += qa.z * k1.z; d01 += qa.w * k1.w;
        d10 += qb.x * k0.x; d10 += qb.y * k0.y; d10 += qb.z * k0.z; d10 += qb.w * k0.w;
        d11 += qb.x * k1.x; d11 += qb.y * k1.y; d11 += qb.z * k1.z; d11 += qb.w * k1.w;
      }
      Ps[rowA * PST + cg]      = (2.f + 2.f * d00) * inv_scale + bias;
      Ps[rowA * PST + cg + 32] = (2.f + 2.f * d01) * inv_scale + bias;
      Ps[rowB * PST + cg]      = (2.f + 2.f * d10) * inv_scale + bias;
      Ps[rowB * PST + cg + 32] = (2.f + 2.f * d11) * inv_scale + bias;
    }
    __syncthreads();

    // ---- online softmax: (row, g) = (tid>>4, tid&15), 4 cols each ----
    {
      const int srow = tid >> 4, g = tid & 15;
      float* prow = Ps + srow * PST;
      float x0 = prow[4 * g + 0], x1 = prow[4 * g + 1];
      float x2 = prow[4 * g + 2], x3 = prow[4 * g + 3];
      float tmax = fmaxf(fmaxf(x0, x1), fmaxf(x2, x3));
#pragma unroll
      for (int off = 1; off < 16; off <<= 1)
        tmax = fmaxf(tmax, __shfl_xor(tmax, off, 16));
      const float mold = mrunS[srow];
      const float mnew = fmaxf(mold, tmax);
      float e0 = expf(x0 - mnew), e1 = expf(x1 - mnew);
      float e2 = expf(x2 - mnew), e3 = expf(x3 - mnew);
      prow[4 * g + 0] = e0; prow[4 * g + 1] = e1;
      prow[4 * g + 2] = e2; prow[4 * g + 3] = e3;
      float tsum = (e0 + e1) + (e2 + e3);
#pragma unroll
      for (int off = 1; off < 16; off <<= 1)
        tsum += __shfl_xor(tsum, off, 16);
      if (g == 0) {
        const float alpha = expf(mold - mnew);  // first tile: exp(-inf)=0
        alphaS[srow] = alpha;
        mrunS[srow] = mnew;
        lrunS[srow] = lrunS[srow] * alpha + tsum;
      }
    }
    __syncthreads();

    // ---- PV: acc = acc*alpha + P @ V (V == K tile) ----
    {
      const float aA = alphaS[rowA], aB = alphaS[rowB];
#pragma unroll
      for (int e = 0; e < 4; ++e) { acc0[e] *= aA; acc1[e] *= aB; }
      const float4* v4 = (const float4*)Ks;     // stride KST/4 = 33
      const float* pA = Ps + rowA * PST;
      const float* pB = Ps + rowB * PST;
#pragma unroll 4
      for (int m = 0; m < BN; ++m) {
        float4 vv = v4[m * (KST / 4) + cg];
        float pa = pA[m], pb = pB[m];
        acc0[0] += pa * vv.x; acc0[1] += pa * vv.y; acc0[2] += pa * vv.z; acc0[3] += pa * vv.w;
        acc1[0] += pb * vv.x; acc1[1] += pb * vv.y; acc1[2] += pb * vv.z; acc1[3] += pb * vv.w;
      }
      // column 128 handled by a cross-thread pass (no per-iter divergence)
      const int r128 = tid >> 4, mseg = tid & 15;
      float part = 0.f;
#pragma unroll
      for (int j = 0; j < 4; ++j) {
        const int m = mseg * 4 + j;
        part += Ps[r128 * PST + m] * Ks[m * KST + 128];
      }
#pragma unroll
      for (int off = 1; off < 16; off <<= 1)
        part += __shfl_xor(part, off, 16);
      if (mseg == 0) A128[r128] = A128[r128] * alphaS[r128] + part;
    }
  }

  __syncthreads();

  // ---- epilogue: ave = acc/l, then double Lorentz normalization ----
  float* AveS = Qs;  // reuse, stride QST, 16 rows x 129 (+pads)
  {
    const float lA = lrunS[rowA], lB = lrunS[rowB];
    float4* av4 = (float4*)AveS;
    av4[rowA * (QST / 4) + cg] =
        make_float4(acc0[0] / lA, acc0[1] / lA, acc0[2] / lA, acc0[3] / lA);
    av4[rowB * (QST / 4) + cg] =
        make_float4(acc1[0] / lB, acc1[1] / lB, acc1[2] / lB, acc1[3] / lB);
  }
  if (tid < BM) {
    AveS[tid * QST + 128] = A128[tid] / lrunS[tid];
    AveS[tid * QST + 129] = 0.f; AveS[tid * QST + 130] = 0.f; AveS[tid * QST + 131] = 0.f;
  }
  __syncthreads();

  {
    const int row = tid >> 4, g = tid & 15;   // 16 threads per row, cols 8g..8g+7
    float* arow = AveS + row * QST;
    const float4* a4 = (const float4*)arow;
    float4 u = a4[2 * g], w = a4[2 * g + 1];
    float4 z = make_float4(0.f, 0.f, 0.f, 0.f);
    float s0 = u.x * u.x;
    float part = u.y * u.y + u.z * u.z + u.w * u.w
               + w.x * w.x + w.y * w.y + w.z * w.z + w.w * w.w;
    part += (g == 0) ? -s0 : s0;              // d=0 is the Lorentz time coord
    if (g == 0) { z = a4[32]; part += z.x * z.x + z.y * z.y + z.z * z.z + z.w * z.w; }
#pragma unroll
    for (int off = 1; off < 16; off <<= 1) part += __shfl_xor(part, off, 16);
    const float denom1 = sqrtf(fmaxf(fabsf(part), 1e-8f));

    float4 yu, yw; float yz = 0.f;
    yu.x = u.x / denom1; yu.y = u.y / denom1; yu.z = u.z / denom1; yu.w = u.w / denom1;
    yw.x = w.x / denom1; yw.y = w.y / denom1; yw.z = w.z / denom1; yw.w = w.w / denom1;
    float t0 = yu.x * yu.x;
    float p2 = yu.y * yu.y + yu.z * yu.z + yu.w * yu.w
             + yw.x * yw.x + yw.y * yw.y + yw.z * yw.z + yw.w * yw.w;
    p2 += (g == 0) ? -t0 : t0;
    if (g == 0) { yz = z.x / denom1; p2 += yz * yz; }
#pragma unroll
    for (int off = 1; off < 16; off <<= 1) p2 += __shfl_xor(p2, off, 16);
    const float denom2 = sqrtf(fmaxf(fabsf(p2), 1e-8f));

    float* orow = outg + (size_t)(row0 + row) * DD;
    orow[8 * g + 0] = yu.x / denom2;
    orow[8 * g + 1] = yu.y / denom2;
    orow[8 * g + 2] = yu.z / denom2;
    orow[8 * g + 3] = yu.w / denom2;
    orow[8 * g + 4] = yw.x / denom2;
    orow[8 * g + 5] = yw.y / denom2;
    orow[8 * g + 6] = yw.z / denom2;
    orow[8 * g + 7] = yw.w / denom2;
    if (g == 0) orow[128] = yz / denom2;
  }
}

extern "C" void kernel_launch(void* const* d_in, const int* in_sizes, int n_in,
                              void* d_out, int out_size, void* d_ws, size_t ws_size,
                              hipStream_t stream) {
  const float* Qg = (const float*)d_in[0];
  const float* Kg = (const float*)d_in[1];
  const float* sc = (const float*)d_in[2];
  const float* bs = (const float*)d_in[3];
  float* out = (float*)d_out;
  hipLaunchKernelGGL(hyper_attn_kernel, dim3(NQ / BM), dim3(NT), 0, stream,
                     Qg, Kg, sc, bs, out);
}

// Round 2
// 205.136 us; speedup vs baseline: 2.4706x; 2.4706x over previous
//
#include <hip/hip_runtime.h>
#include <hip/hip_bf16.h>
#include <math.h>

// Single-head equivalence (4 identical heads; mean over identical outputs = id).
// Flash attention with fp32-via-split-bf16 MFMA:
//   dot = qh*kh + ql*kh + qh*kl  (error ~2^-17 rel), d=0..127 on matrix cores,
//   d=128 (the +1 Lorentz col) as a rank-1 VALU update.
// Block: 16 queries, 8 waves; wave w handles KV tiles w, w+8, ... (32 rows each)
// with independent online softmax; merged at the end via LDS.

typedef __attribute__((ext_vector_type(8))) short bf16x8;  // 8 bf16 = 4 VGPR
typedef __attribute__((ext_vector_type(4))) float f32x4;

#define NQ 4096
#define DD 129
#define BM 16
#define NWAVE 8
#define NT (NWAVE * 64)
#define TILE 32
#define NSTEP (NQ / (NWAVE * TILE))   // 16
#define VPAD 35                        // padded j-stride (dwords) -> <=2-way banks
#define WREG (128 * VPAD)              // uints per wave LDS region (4480)

__device__ __forceinline__ short f2bf(float x) {
  __hip_bfloat16 h = __float2bfloat16(x);
  return *reinterpret_cast<short*>(&h);
}
__device__ __forceinline__ float bf2f(short b) {
  __hip_bfloat16 h;
  *reinterpret_cast<short*>(&h) = b;
  return __bfloat162float(h);
}

__global__ __launch_bounds__(NT, 2) void hyper_attn_mfma(
    const float* __restrict__ Qg, const float* __restrict__ Kg,
    const float* __restrict__ scale_p, const float* __restrict__ bias_p,
    float* __restrict__ outg)
{
  __shared__ unsigned int VT2[NWAVE * WREG];          // packed (hi|lo) V tiles
  __shared__ float mS[NWAVE][BM], lS[NWAVE][BM], aS[NWAVE][BM];

  const int tid  = threadIdx.x;
  const int wid  = tid >> 6;
  const int lane = tid & 63;
  const int g    = lane >> 4;   // 0..3
  const int c    = lane & 15;   // 0..15
  const int row0 = blockIdx.x * BM;

  const float sA = 2.0f / scale_p[0];
  const float sB = sA + bias_p[0];          // S = dot*sA + sB

  // ---- Q fragments in registers: lane holds qm[row0+c][32cc+8g+e] ----
  bf16x8 qh[4], ql[4];
  const int qrow = row0 + c;
  const float q128 = Qg[qrow * DD + 128];
#pragma unroll
  for (int cc = 0; cc < 4; ++cc) {
#pragma unroll
    for (int e = 0; e < 8; ++e) {
      const int d = 32 * cc + 8 * g + e;
      float v = Qg[qrow * DD + d];
      if (d == 0) v = -v;                   // Lorentz time coord
      const short hb = f2bf(v);
      const float hf = bf2f(hb);
      qh[cc][e] = hb;
      ql[cc][e] = f2bf(v - hf);
    }
  }

  f32x4 accO[8];
#pragma unroll
  for (int i = 0; i < 8; ++i) accO[i] = (f32x4){0.f, 0.f, 0.f, 0.f};
  float m_run = -INFINITY, l_run = 0.f, a128 = 0.f;

  unsigned int* Vw = VT2 + wid * WREG;

  for (int t = 0; t < NSTEP; ++t) {
    const int j0 = (t * NWAVE + wid) * TILE;
    const int rA = j0 + c;
    const int rB = j0 + 16 + c;
    const float k1_128 = Kg[rA * DD + 128];
    const float k2_128 = Kg[rB * DD + 128];

    f32x4 s1acc = (f32x4){0.f, 0.f, 0.f, 0.f};
    f32x4 s2acc = (f32x4){0.f, 0.f, 0.f, 0.f};

#pragma unroll
    for (int cc = 0; cc < 4; ++cc) {
      bf16x8 kh1, kl1, kh2, kl2;
      unsigned int pw1[8], pw2[8];
#pragma unroll
      for (int e = 0; e < 8; ++e) {
        const int d = 32 * cc + 8 * g + e;
        const float v1 = Kg[rA * DD + d];
        const float v2 = Kg[rB * DD + d];
        const short h1 = f2bf(v1); const float hf1 = bf2f(h1);
        const short o1 = f2bf(v1 - hf1);
        const short h2 = f2bf(v2); const float hf2 = bf2f(h2);
        const short o2 = f2bf(v2 - hf2);
        kh1[e] = h1; kl1[e] = o1; kh2[e] = h2; kl2[e] = o2;
        pw1[e] = (unsigned int)(unsigned short)h1 |
                 ((unsigned int)(unsigned short)o1 << 16);
        pw2[e] = (unsigned int)(unsigned short)h2 |
                 ((unsigned int)(unsigned short)o2 << 16);
      }
      // S^T tiles: mfma(K, Q): A row = KV row (l&15), B col = query (l&15)
      s1acc = __builtin_amdgcn_mfma_f32_16x16x32_bf16(kh1, qh[cc], s1acc, 0, 0, 0);
      s1acc = __builtin_amdgcn_mfma_f32_16x16x32_bf16(kh1, ql[cc], s1acc, 0, 0, 0);
      s1acc = __builtin_amdgcn_mfma_f32_16x16x32_bf16(kl1, qh[cc], s1acc, 0, 0, 0);
      s2acc = __builtin_amdgcn_mfma_f32_16x16x32_bf16(kh2, qh[cc], s2acc, 0, 0, 0);
      s2acc = __builtin_amdgcn_mfma_f32_16x16x32_bf16(kh2, ql[cc], s2acc, 0, 0, 0);
      s2acc = __builtin_amdgcn_mfma_f32_16x16x32_bf16(kl2, qh[cc], s2acc, 0, 0, 0);
      // stage packed V (hi|lo) transposed-consumable: word idx = d*VPAD + j
#pragma unroll
      for (int e = 0; e < 8; ++e) {
        const int d = 32 * cc + 8 * g + e;
        Vw[d * VPAD + c]      = pw1[e];
        Vw[d * VPAD + 16 + c] = pw2[e];
      }
    }

    // ---- finalize S (affine + d=128 rank-1), online softmax ----
    float s1[4], s2[4], kk1[4], kk2[4];
#pragma unroll
    for (int r = 0; r < 4; ++r) {
      kk1[r] = __shfl(k1_128, 4 * g + r);
      kk2[r] = __shfl(k2_128, 4 * g + r);
      s1[r] = (s1acc[r] + q128 * kk1[r]) * sA + sB;
      s2[r] = (s2acc[r] + q128 * kk2[r]) * sA + sB;
    }
    float tmax = fmaxf(fmaxf(fmaxf(s1[0], s1[1]), fmaxf(s1[2], s1[3])),
                       fmaxf(fmaxf(s2[0], s2[1]), fmaxf(s2[2], s2[3])));
    tmax = fmaxf(tmax, __shfl_xor(tmax, 16));
    tmax = fmaxf(tmax, __shfl_xor(tmax, 32));
    const float m_new = fmaxf(m_run, tmax);

    float p1[4], p2[4], tsum = 0.f;
#pragma unroll
    for (int r = 0; r < 4; ++r) {
      p1[r] = __expf(s1[r] - m_new);
      p2[r] = __expf(s2[r] - m_new);
      tsum += p1[r] + p2[r];
    }
    tsum += __shfl_xor(tsum, 16);
    tsum += __shfl_xor(tsum, 32);
    const float alpha = __expf(m_run - m_new);   // first step: exp(-inf)=0
    l_run = l_run * alpha + tsum;
    m_run = m_new;

    float dp = 0.f;
#pragma unroll
    for (int r = 0; r < 4; ++r) dp += p1[r] * kk1[r] + p2[r] * kk2[r];
    a128 = a128 * alpha + dp;

    float ar[4];
#pragma unroll
    for (int r = 0; r < 4; ++r) ar[r] = __shfl(alpha, 4 * g + r);
#pragma unroll
    for (int dt = 0; dt < 8; ++dt) {
#pragma unroll
      for (int r = 0; r < 4; ++r) accO[dt][r] *= ar[r];
    }

    // P fragment: k-slot (g,e): e<4 -> j=4g+e (tile1), e>=4 -> j=16+4g+(e-4)
    bf16x8 pa;
#pragma unroll
    for (int r = 0; r < 4; ++r) {
      pa[r]     = f2bf(p1[r]);
      pa[4 + r] = f2bf(p2[r]);
    }

    // ---- PV: acc[q][d] += P @ (Vhi + Vlo) ----
#pragma unroll
    for (int dt = 0; dt < 8; ++dt) {
      const int dbase = (dt * 16 + c) * VPAD;
      bf16x8 vh, vl;
#pragma unroll
      for (int i = 0; i < 4; ++i) {
        const unsigned int w1 = Vw[dbase + 4 * g + i];
        const unsigned int w2 = Vw[dbase + 16 + 4 * g + i];
        vh[i]     = (short)(w1 & 0xffffu);
        vl[i]     = (short)(w1 >> 16);
        vh[4 + i] = (short)(w2 & 0xffffu);
        vl[4 + i] = (short)(w2 >> 16);
      }
      accO[dt] = __builtin_amdgcn_mfma_f32_16x16x32_bf16(pa, vh, accO[dt], 0, 0, 0);
      accO[dt] = __builtin_amdgcn_mfma_f32_16x16x32_bf16(pa, vl, accO[dt], 0, 0, 0);
    }
  }

  // ---- write per-wave partials; merge across 8 waves ----
  float* Ow = reinterpret_cast<float*>(Vw);
#pragma unroll
  for (int dt = 0; dt < 8; ++dt) {
#pragma unroll
    for (int r = 0; r < 4; ++r)
      Ow[(4 * g + r) * 128 + dt * 16 + c] = accO[dt][r];
  }
  a128 += __shfl_xor(a128, 16);
  a128 += __shfl_xor(a128, 32);
  if (lane < 16) {
    mS[wid][lane] = m_run;
    lS[wid][lane] = l_run;
    aS[wid][lane] = a128;
  }
  __syncthreads();

  {
    const int q = tid >> 5;       // 0..15
    const int s = tid & 31;       // 4 d-cols each
    float M = -INFINITY;
#pragma unroll
    for (int w = 0; w < NWAVE; ++w) M = fmaxf(M, mS[w][q]);
    float ew[NWAVE], L = 0.f;
#pragma unroll
    for (int w = 0; w < NWAVE; ++w) {
      ew[w] = __expf(mS[w][q] - M);
      L += ew[w] * lS[w][q];
    }
    float o[4] = {0.f, 0.f, 0.f, 0.f};
    float A = 0.f;
#pragma unroll
    for (int w = 0; w < NWAVE; ++w) {
      const float* Op =
          reinterpret_cast<const float*>(VT2 + w * WREG) + q * 128 + 4 * s;
#pragma unroll
      for (int i = 0; i < 4; ++i) o[i] += Op[i] * ew[w];
      A += aS[w][q] * ew[w];
    }
    const float invL = 1.0f / L;
#pragma unroll
    for (int i = 0; i < 4; ++i) o[i] *= invL;
    A *= invL;

    // Lorentz normalize twice (as reference does)
    float part = o[0] * o[0] + o[1] * o[1] + o[2] * o[2] + o[3] * o[3];
    if (s == 0) part += -2.f * o[0] * o[0] + A * A;   // d0 negated; d128 added
    part += __shfl_xor(part, 1);
    part += __shfl_xor(part, 2);
    part += __shfl_xor(part, 4);
    part += __shfl_xor(part, 8);
    part += __shfl_xor(part, 16);
    const float den1 = sqrtf(fmaxf(fabsf(part), 1e-8f));

    float y[4];
#pragma unroll
    for (int i = 0; i < 4; ++i) y[i] = o[i] / den1;
    const float yT = A / den1;

    float p2s = y[0] * y[0] + y[1] * y[1] + y[2] * y[2] + y[3] * y[3];
    if (s == 0) p2s += -2.f * y[0] * y[0] + yT * yT;
    p2s += __shfl_xor(p2s, 1);
    p2s += __shfl_xor(p2s, 2);
    p2s += __shfl_xor(p2s, 4);
    p2s += __shfl_xor(p2s, 8);
    p2s += __shfl_xor(p2s, 16);
    const float den2 = sqrtf(fmaxf(fabsf(p2s), 1e-8f));

    float* orow = outg + (size_t)(row0 + q) * DD + 4 * s;
#pragma unroll
    for (int i = 0; i < 4; ++i) orow[i] = y[i] / den2;
    if (s == 0) outg[(size_t)(row0 + q) * DD + 128] = yT / den2;
  }
}

extern "C" void kernel_launch(void* const* d_in, const int* in_sizes, int n_in,
                              void* d_out, int out_size, void* d_ws, size_t ws_size,
                              hipStream_t stream) {
  const float* Qg = (const float*)d_in[0];
  const float* Kg = (const float*)d_in[1];
  const float* sc = (const float*)d_in[2];
  const float* bs = (const float*)d_in[3];
  float* out = (float*)d_out;
  hipLaunchKernelGGL(hyper_attn_mfma, dim3(NQ / BM), dim3(NT), 0, stream,
                     Qg, Kg, sc, bs, out);
}

// Round 3
// 199.788 us; speedup vs baseline: 2.5368x; 1.0268x over previous
//
#include <hip/hip_runtime.h>
#include <hip/hip_bf16.h>
#include <math.h>

// Single-head equivalence (4 identical heads; mean over identical outputs = id).
// Pipeline: prepass (K -> bf16 hi/lo planes, row-major + transposed/permuted)
//           attn_split (flash attention, split-bf16 MFMA, KV split 2-way)
//           merge_norm (combine splits + double Lorentz normalization)

typedef __attribute__((ext_vector_type(8))) short bf16x8;  // 8 bf16 = 4 VGPR
typedef __attribute__((ext_vector_type(4))) float f32x4;

#define NQ 4096
#define DD 129
#define BM 16
#define NWAVE 8
#define NT 512
#define TILE 32
#define NSPLIT 2
#define KVHALF (NQ / NSPLIT)                  // 2048
#define NSTEP (KVHALF / (NWAVE * TILE))       // 8

// d_ws byte offsets
#define WS_KH  ((size_t)0)
#define WS_KL  ((size_t)1 << 20)
#define WS_VTH ((size_t)2 << 20)
#define WS_VTL ((size_t)3 << 20)
#define WS_OP  ((size_t)4 << 20)              // 256*2*16*128 f32 = 4 MB
#define WS_MLA ((size_t)8 << 20)              // 256*2*48 f32 = 96 KB

__device__ __forceinline__ short f2bf(float x) {
  __hip_bfloat16 h = __float2bfloat16(x);
  return *reinterpret_cast<short*>(&h);
}
__device__ __forceinline__ float bf2f(short b) {
  __hip_bfloat16 h;
  *reinterpret_cast<short*>(&h) = b;
  return __bfloat162float(h);
}

// ---------------- prepass: K -> Kh/Kl (row) + VTh/VTl (col, k-slot-permuted) --
__global__ __launch_bounds__(256) void prepass(
    const float* __restrict__ Kg,
    short* __restrict__ Kh, short* __restrict__ Kl,
    short* __restrict__ VTh, short* __restrict__ VTl)
{
  const int nthr = gridDim.x * blockDim.x;
  const int tid0 = blockIdx.x * blockDim.x + threadIdx.x;
  // row-major planes (coalesced writes)
  for (int i = tid0; i < NQ * 128; i += nthr) {
    const int r = i >> 7, d = i & 127;
    const float v = Kg[r * DD + d];
    const short h = f2bf(v);
    Kh[i] = h;
    Kl[i] = f2bf(v - bf2f(h));
  }
  // transposed planes, permuted so PV B-frag k-slots are contiguous:
  // slot p = 8g+e  <->  j-in-tile = 4g+e (e<4) | 16+4g+(e-4) (e>=4)
  for (int i = tid0; i < NQ * 128; i += nthr) {
    const int d = i >> 12, j = i & 4095;
    const float v = Kg[j * DD + d];
    const short h = f2bf(v);
    const short l = f2bf(v - bf2f(h));
    const int jj = j & 31;
    const int p = (jj < 16) ? ((jj >> 2) * 8 + (jj & 3))
                            : (((jj - 16) >> 2) * 8 + 4 + (jj & 3));
    const int idx = d * NQ + (j & ~31) + p;
    VTh[idx] = h;
    VTl[idx] = l;
  }
}

// ---------------- main flash-attention kernel (one KV half per block) --------
__global__ __launch_bounds__(NT, 4) void attn_split(
    const float* __restrict__ Qg, const float* __restrict__ Kg,
    const short* __restrict__ Kh, const short* __restrict__ Kl,
    const short* __restrict__ VTh, const short* __restrict__ VTl,
    const float* __restrict__ scale_p, const float* __restrict__ bias_p,
    float* __restrict__ OP, float* __restrict__ MLA)
{
  __shared__ float OwS[4][BM * 128];          // 32 KB two-phase merge buffer
  __shared__ float mS[NWAVE][BM], lS[NWAVE][BM], aS[NWAVE][BM];

  const int tid  = threadIdx.x;
  const int wid  = tid >> 6;
  const int lane = tid & 63;
  const int g    = lane >> 4;   // 0..3
  const int c    = lane & 15;   // 0..15
  const int qg   = blockIdx.x;
  const int sp   = blockIdx.y;
  const int row0 = qg * BM;

  const float sA = 2.0f / scale_p[0];
  const float sB = sA + bias_p[0];            // S = dot*sA + sB

  // Q fragments (one-time scalar conversion; d=0 Lorentz-negated)
  bf16x8 qh[4], ql[4];
  const int qrow = row0 + c;
  const float q128 = Qg[qrow * DD + 128];
#pragma unroll
  for (int cc = 0; cc < 4; ++cc) {
#pragma unroll
    for (int e = 0; e < 8; ++e) {
      const int d = 32 * cc + 8 * g + e;
      float v = Qg[qrow * DD + d];
      if (d == 0) v = -v;
      const short hb = f2bf(v);
      qh[cc][e] = hb;
      ql[cc][e] = f2bf(v - bf2f(hb));
    }
  }

  f32x4 accO[8];
#pragma unroll
  for (int i = 0; i < 8; ++i) accO[i] = (f32x4){0.f, 0.f, 0.f, 0.f};
  float m_run = -INFINITY, l_run = 0.f, a128 = 0.f;

  for (int t = 0; t < NSTEP; ++t) {
    const int j0 = sp * KVHALF + (t * NWAVE + wid) * TILE;
    const int rA = j0 + c, rB = rA + 16;
    const float k1_128 = Kg[rA * DD + 128];
    const float k2_128 = Kg[rB * DD + 128];

    // ---- S^T = mfma(K, Q), 3-term split-bf16, rows rA then rB ----
    f32x4 s1acc = (f32x4){0.f, 0.f, 0.f, 0.f};
    f32x4 s2acc = (f32x4){0.f, 0.f, 0.f, 0.f};
    {
      const short* KhA = Kh + rA * 128 + 8 * g;
      const short* KlA = Kl + rA * 128 + 8 * g;
#pragma unroll
      for (int cc = 0; cc < 4; ++cc) {
        const bf16x8 kh = *(const bf16x8*)(KhA + 32 * cc);
        const bf16x8 kl = *(const bf16x8*)(KlA + 32 * cc);
        s1acc = __builtin_amdgcn_mfma_f32_16x16x32_bf16(kh, qh[cc], s1acc, 0, 0, 0);
        s1acc = __builtin_amdgcn_mfma_f32_16x16x32_bf16(kh, ql[cc], s1acc, 0, 0, 0);
        s1acc = __builtin_amdgcn_mfma_f32_16x16x32_bf16(kl, qh[cc], s1acc, 0, 0, 0);
      }
      const short* KhB = Kh + rB * 128 + 8 * g;
      const short* KlB = Kl + rB * 128 + 8 * g;
#pragma unroll
      for (int cc = 0; cc < 4; ++cc) {
        const bf16x8 kh = *(const bf16x8*)(KhB + 32 * cc);
        const bf16x8 kl = *(const bf16x8*)(KlB + 32 * cc);
        s2acc = __builtin_amdgcn_mfma_f32_16x16x32_bf16(kh, qh[cc], s2acc, 0, 0, 0);
        s2acc = __builtin_amdgcn_mfma_f32_16x16x32_bf16(kh, ql[cc], s2acc, 0, 0, 0);
        s2acc = __builtin_amdgcn_mfma_f32_16x16x32_bf16(kl, qh[cc], s2acc, 0, 0, 0);
      }
    }

    // ---- finalize S (affine + d=128 rank-1), online softmax ----
    float s1[4], s2[4], kk1[4], kk2[4];
#pragma unroll
    for (int r = 0; r < 4; ++r) {
      kk1[r] = __shfl(k1_128, 4 * g + r);
      kk2[r] = __shfl(k2_128, 4 * g + r);
      s1[r] = (s1acc[r] + q128 * kk1[r]) * sA + sB;
      s2[r] = (s2acc[r] + q128 * kk2[r]) * sA + sB;
    }
    float tmax = fmaxf(fmaxf(fmaxf(s1[0], s1[1]), fmaxf(s1[2], s1[3])),
                       fmaxf(fmaxf(s2[0], s2[1]), fmaxf(s2[2], s2[3])));
    tmax = fmaxf(tmax, __shfl_xor(tmax, 16));
    tmax = fmaxf(tmax, __shfl_xor(tmax, 32));
    const float m_old = m_run;
    const float m_new = fmaxf(m_old, tmax);

    float p1[4], p2[4], tsum = 0.f;
#pragma unroll
    for (int r = 0; r < 4; ++r) {
      p1[r] = __expf(s1[r] - m_new);
      p2[r] = __expf(s2[r] - m_new);
      tsum += p1[r] + p2[r];
    }
    tsum += __shfl_xor(tsum, 16);
    tsum += __shfl_xor(tsum, 32);
    const float alpha = __expf(m_old - m_new);
    l_run = l_run * alpha + tsum;
    m_run = m_new;

    float dp = 0.f;
#pragma unroll
    for (int r = 0; r < 4; ++r) dp += p1[r] * kk1[r] + p2[r] * kk2[r];
    a128 = a128 * alpha + dp;

    if (__any(m_new > m_old)) {        // defer-rescale: skip when alpha==1 everywhere
      float ar[4];
#pragma unroll
      for (int r = 0; r < 4; ++r) ar[r] = __shfl(alpha, 4 * g + r);
#pragma unroll
      for (int dt = 0; dt < 8; ++dt) {
#pragma unroll
        for (int r = 0; r < 4; ++r) accO[dt][r] *= ar[r];
      }
    }

    // P fragment: slot e=r -> j=4g+r (rows rA-half), e=4+r -> j=16+4g+r
    bf16x8 pa;
#pragma unroll
    for (int r = 0; r < 4; ++r) {
      pa[r]     = f2bf(p1[r]);
      pa[4 + r] = f2bf(p2[r]);
    }

    // ---- PV: direct contiguous B-frag loads from permuted VT planes ----
    const short* Vh0 = VTh + j0 + 8 * g;
    const short* Vl0 = VTl + j0 + 8 * g;
#pragma unroll
    for (int dt = 0; dt < 8; ++dt) {
      const int drow = (dt * 16 + c) * NQ;
      const bf16x8 vh = *(const bf16x8*)(Vh0 + drow);
      const bf16x8 vl = *(const bf16x8*)(Vl0 + drow);
      accO[dt] = __builtin_amdgcn_mfma_f32_16x16x32_bf16(pa, vh, accO[dt], 0, 0, 0);
      accO[dt] = __builtin_amdgcn_mfma_f32_16x16x32_bf16(pa, vl, accO[dt], 0, 0, 0);
    }
  }

  // ---- merge 8 waves (two-phase, 32 KB LDS), write split partial ----
  a128 += __shfl_xor(a128, 16);
  a128 += __shfl_xor(a128, 32);
  if (lane < 16) mS[wid][lane] = m_run;
  __syncthreads();

  float M = mS[0][c];
#pragma unroll
  for (int w = 1; w < NWAVE; ++w) M = fmaxf(M, mS[w][c]);
  const float ew = __expf(m_run - M);
  if (lane < 16) { lS[wid][lane] = l_run * ew; aS[wid][lane] = a128 * ew; }

  float ewr[4];
#pragma unroll
  for (int r = 0; r < 4; ++r) ewr[r] = __shfl(ew, 4 * g + r);
#pragma unroll
  for (int dt = 0; dt < 8; ++dt) {
#pragma unroll
    for (int r = 0; r < 4; ++r) accO[dt][r] *= ewr[r];
  }

  if (wid < 4) {
#pragma unroll
    for (int dt = 0; dt < 8; ++dt)
#pragma unroll
      for (int r = 0; r < 4; ++r)
        OwS[wid][(4 * g + r) * 128 + dt * 16 + c] = accO[dt][r];
  }
  __syncthreads();
  if (wid >= 4) {
#pragma unroll
    for (int dt = 0; dt < 8; ++dt)
#pragma unroll
      for (int r = 0; r < 4; ++r)
        OwS[wid - 4][(4 * g + r) * 128 + dt * 16 + c] += accO[dt][r];
  }
  __syncthreads();

  {
    const int q = tid >> 5, s = tid & 31;
    f32x4 o = *(const f32x4*)&OwS[0][q * 128 + 4 * s];
#pragma unroll
    for (int i = 1; i < 4; ++i) {
      const f32x4 oi = *(const f32x4*)&OwS[i][q * 128 + 4 * s];
#pragma unroll
      for (int e = 0; e < 4; ++e) o[e] += oi[e];
    }
    float L = 0.f, A = 0.f, Mq = -INFINITY;
#pragma unroll
    for (int w = 0; w < NWAVE; ++w) {
      L += lS[w][q]; A += aS[w][q]; Mq = fmaxf(Mq, mS[w][q]);
    }
    float* dst = OP + ((size_t)(qg * NSPLIT + sp) * BM + q) * 128 + 4 * s;
    *(f32x4*)dst = o;
    if (s == 0) {
      float* mla = MLA + (size_t)(qg * NSPLIT + sp) * 48;
      mla[q] = Mq; mla[16 + q] = L; mla[32 + q] = A;
    }
  }
}

// ---------------- merge splits + double Lorentz normalization ----------------
__global__ __launch_bounds__(256) void merge_norm(
    const float* __restrict__ OP, const float* __restrict__ MLA,
    float* __restrict__ outg)
{
  const int qg  = blockIdx.x;
  const int rq  = threadIdx.x >> 4;   // 0..15
  const int seg = threadIdx.x & 15;   // 8 d-cols each

  const float* a0 = MLA + (size_t)(qg * 2 + 0) * 48;
  const float* a1 = MLA + (size_t)(qg * 2 + 1) * 48;
  const float m1 = a0[rq], l1 = a0[16 + rq], A1 = a0[32 + rq];
  const float m2 = a1[rq], l2 = a1[16 + rq], A2 = a1[32 + rq];
  const float M  = fmaxf(m1, m2);
  const float w1 = __expf(m1 - M), w2 = __expf(m2 - M);
  const float invL = 1.0f / (w1 * l1 + w2 * l2);

  const float* O1 = OP + ((size_t)(qg * 2 + 0) * 16 + rq) * 128 + 8 * seg;
  const float* O2 = OP + ((size_t)(qg * 2 + 1) * 16 + rq) * 128 + 8 * seg;
  float o[8];
#pragma unroll
  for (int i = 0; i < 8; ++i) o[i] = (w1 * O1[i] + w2 * O2[i]) * invL;
  const float A = (w1 * A1 + w2 * A2) * invL;

  float part = 0.f;
#pragma unroll
  for (int i = 0; i < 8; ++i) part += o[i] * o[i];
  if (seg == 0) part += -2.f * o[0] * o[0] + A * A;   // d0 negated, d128 added
  part += __shfl_xor(part, 1);
  part += __shfl_xor(part, 2);
  part += __shfl_xor(part, 4);
  part += __shfl_xor(part, 8);
  const float den1 = sqrtf(fmaxf(fabsf(part), 1e-8f));

  float y[8];
#pragma unroll
  for (int i = 0; i < 8; ++i) y[i] = o[i] / den1;
  const float yA = A / den1;

  float p2 = 0.f;
#pragma unroll
  for (int i = 0; i < 8; ++i) p2 += y[i] * y[i];
  if (seg == 0) p2 += -2.f * y[0] * y[0] + yA * yA;
  p2 += __shfl_xor(p2, 1);
  p2 += __shfl_xor(p2, 2);
  p2 += __shfl_xor(p2, 4);
  p2 += __shfl_xor(p2, 8);
  const float den2 = sqrtf(fmaxf(fabsf(p2), 1e-8f));

  float* orow = outg + (size_t)(qg * 16 + rq) * DD;
#pragma unroll
  for (int i = 0; i < 8; ++i) orow[8 * seg + i] = y[i] / den2;
  if (seg == 0) orow[128] = yA / den2;
}

extern "C" void kernel_launch(void* const* d_in, const int* in_sizes, int n_in,
                              void* d_out, int out_size, void* d_ws, size_t ws_size,
                              hipStream_t stream) {
  const float* Qg = (const float*)d_in[0];
  const float* Kg = (const float*)d_in[1];
  const float* sc = (const float*)d_in[2];
  const float* bs = (const float*)d_in[3];
  float* out = (float*)d_out;

  char* ws = (char*)d_ws;
  short* Kh  = (short*)(ws + WS_KH);
  short* Kl  = (short*)(ws + WS_KL);
  short* VTh = (short*)(ws + WS_VTH);
  short* VTl = (short*)(ws + WS_VTL);
  float* OP  = (float*)(ws + WS_OP);
  float* MLA = (float*)(ws + WS_MLA);

  hipLaunchKernelGGL(prepass, dim3(1024), dim3(256), 0, stream, Kg, Kh, Kl, VTh, VTl);
  hipLaunchKernelGGL(attn_split, dim3(NQ / BM, NSPLIT), dim3(NT), 0, stream,
                     Qg, Kg, Kh, Kl, VTh, VTl, sc, bs, OP, MLA);
  hipLaunchKernelGGL(merge_norm, dim3(NQ / BM), dim3(256), 0, stream, OP, MLA, out);
}

// Round 5
// 133.750 us; speedup vs baseline: 3.7893x; 1.4938x over previous
//
#include <hip/hip_runtime.h>
#include <math.h>

// Single-head equivalence (4 identical heads; mean over identical outputs = id).
// Round 4 (re-submit; round-4 bench was lost to GPU acquisition timeout):
// fp16 single-plane MFMA flash attention.
//   prepass:  K -> fp16 row plane Kh, fp16 transposed+slot-permuted plane VT,
//             dense fp32 K128 column (kills the stride-516B gathers).
//   attn:     16 queries/block, 8 waves split KV, NSPLIT=2 KV halves,
//             XCD-pinned split for L2 locality. No LDS in main loop.
//   merge:    combine 2 splits + double Lorentz normalization.

typedef __attribute__((ext_vector_type(8))) _Float16 f16x8;
typedef __attribute__((ext_vector_type(8))) short short8;
typedef __attribute__((ext_vector_type(4))) float f32x4;

#define NQ 4096
#define DD 129
#define BM 16
#define NWAVE 8
#define NT 512
#define TILE 32
#define NSPLIT 2
#define KVSEG (NQ / NSPLIT)              // 2048
#define NSTEP (KVSEG / (NWAVE * TILE))   // 8
#define NQG (NQ / BM)                    // 256

// d_ws byte offsets
#define WS_KH   ((size_t)0)              // NQ*128 fp16 = 1 MB
#define WS_VT   ((size_t)1 << 20)        // 128*NQ fp16 = 1 MB (transposed, permuted)
#define WS_K128 ((size_t)2 << 20)        // NQ fp32 = 16 KB
#define WS_OP   ((size_t)3 << 20)        // NQG*NSPLIT*16*128 f32 = 4 MB
#define WS_MLA  ((size_t)7 << 20)        // NQG*NSPLIT*48 f32 = 96 KB

__device__ __forceinline__ short f2h_bits(float x) {
  _Float16 h = (_Float16)x;
  return *reinterpret_cast<short*>(&h);
}

// ---------------- prepass: coalesced via LDS transpose tile ------------------
__global__ __launch_bounds__(256) void prepass(
    const float* __restrict__ Kg,
    short* __restrict__ Kh, short* __restrict__ VT, float* __restrict__ K128)
{
  __shared__ short tile[32][128];
  const int t  = threadIdx.x;
  const int j0 = blockIdx.x * 32;

  // phase 1: rows j0..j0+31, coalesced reads, fp16 convert, row-plane store
#pragma unroll
  for (int i = 0; i < 2; ++i) {
    const int idx = t + 256 * i;        // 0..511
    const int r   = idx >> 4;           // 0..31
    const int d0  = (idx & 15) * 8;
    const float* src = Kg + (size_t)(j0 + r) * DD + d0;
    short8 sv;
#pragma unroll
    for (int e = 0; e < 8; ++e) {
      const short s = f2h_bits(src[e]);
      sv[e] = s;
      tile[r][d0 + e] = s;
    }
    *reinterpret_cast<short8*>(Kh + (size_t)(j0 + r) * 128 + d0) = sv;
  }
  if (t < 32) K128[j0 + t] = Kg[(size_t)(j0 + t) * DD + 128];
  __syncthreads();

  // phase 2: transposed + k-slot-permuted plane. slot p=8g+e <-> j-in-group:
  //   e<4 -> 4g+e ; e>=4 -> 16+4g+(e-4)
  {
    const int d = t >> 1, half = t & 1;
    short v[16];
#pragma unroll
    for (int i = 0; i < 16; ++i) {
      const int p = 16 * half + i;
      const int g = p >> 3, e = p & 7;
      const int j = (e < 4) ? (4 * g + e) : (16 + 4 * g + (e - 4));
      v[i] = tile[j][d];
    }
    short8 s0, s1;
#pragma unroll
    for (int i = 0; i < 8; ++i) { s0[i] = v[i]; s1[i] = v[8 + i]; }
    short* dst = VT + (size_t)d * NQ + j0 + 16 * half;
    *reinterpret_cast<short8*>(dst)     = s0;
    *reinterpret_cast<short8*>(dst + 8) = s1;
  }
}

// ---------------- main flash-attention kernel --------------------------------
__global__ __launch_bounds__(NT, 4) void attn_split(
    const float* __restrict__ Qg,
    const short* __restrict__ Kh, const short* __restrict__ VT,
    const float* __restrict__ K128,
    const float* __restrict__ scale_p, const float* __restrict__ bias_p,
    float* __restrict__ OP, float* __restrict__ MLA)
{
  __shared__ float OwS[4][BM * 128];
  __shared__ float mS[NWAVE][BM], lS[NWAVE][BM], aS[NWAVE][BM];

  // XCD-pinned bijection: bid -> (qg, sp); all blocks on one XCD share sp.
  const int bid = blockIdx.x;          // 0..511
  const int xcd = bid & 7;
  const int sp  = xcd & 1;
  const int qg  = ((xcd >> 1) << 6) + (bid >> 3);   // 0..255, bijective

  const int tid  = threadIdx.x;
  const int wid  = tid >> 6;
  const int lane = tid & 63;
  const int g    = lane >> 4;   // 0..3
  const int c    = lane & 15;   // 0..15
  const int row0 = qg * BM;

  const float sA = 2.0f / scale_p[0];
  const float sB = sA + bias_p[0];     // S = dot*sA + sB

  // Q fragments (fp16), d=0 Lorentz-negated
  f16x8 qf[4];
  const int qrow = row0 + c;
  const float q128 = Qg[(size_t)qrow * DD + 128];
#pragma unroll
  for (int cc = 0; cc < 4; ++cc) {
#pragma unroll
    for (int e = 0; e < 8; ++e) {
      const int d = 32 * cc + 8 * g + e;
      float v = Qg[(size_t)qrow * DD + d];
      if (d == 0) v = -v;
      qf[cc][e] = (_Float16)v;
    }
  }

  f32x4 accO[8];
#pragma unroll
  for (int i = 0; i < 8; ++i) accO[i] = (f32x4){0.f, 0.f, 0.f, 0.f};
  float m_run = -INFINITY, l_run = 0.f, a128 = 0.f;

  for (int t = 0; t < NSTEP; ++t) {
    const int j0 = sp * KVSEG + (t * NWAVE + wid) * TILE;
    const int rA = j0 + c, rB = rA + 16;

    // V fragments: independent of S chain -> issue first (overlap)
    f16x8 vf[8];
#pragma unroll
    for (int dt = 0; dt < 8; ++dt)
      vf[dt] = *reinterpret_cast<const f16x8*>(
          VT + (size_t)(dt * 16 + c) * NQ + j0 + 8 * g);

    // dense, coalesced d=128 column loads (16B, broadcast across lanes)
    const f32x4 kk1 = *reinterpret_cast<const f32x4*>(K128 + j0 + 4 * g);
    const f32x4 kk2 = *reinterpret_cast<const f32x4*>(K128 + j0 + 16 + 4 * g);

    // ---- S^T = mfma(K, Q), fp16 ----
    f32x4 s1acc = (f32x4){0.f, 0.f, 0.f, 0.f};
    f32x4 s2acc = (f32x4){0.f, 0.f, 0.f, 0.f};
    const short* KA = Kh + (size_t)rA * 128 + 8 * g;
    const short* KB = Kh + (size_t)rB * 128 + 8 * g;
#pragma unroll
    for (int cc = 0; cc < 4; ++cc)
      s1acc = __builtin_amdgcn_mfma_f32_16x16x32_f16(
          *reinterpret_cast<const f16x8*>(KA + 32 * cc), qf[cc], s1acc, 0, 0, 0);
#pragma unroll
    for (int cc = 0; cc < 4; ++cc)
      s2acc = __builtin_amdgcn_mfma_f32_16x16x32_f16(
          *reinterpret_cast<const f16x8*>(KB + 32 * cc), qf[cc], s2acc, 0, 0, 0);

    // ---- finalize S (affine + d=128 rank-1), online softmax ----
    float s1[4], s2[4];
#pragma unroll
    for (int r = 0; r < 4; ++r) {
      s1[r] = (s1acc[r] + q128 * kk1[r]) * sA + sB;
      s2[r] = (s2acc[r] + q128 * kk2[r]) * sA + sB;
    }
    float tmax = fmaxf(fmaxf(fmaxf(s1[0], s1[1]), fmaxf(s1[2], s1[3])),
                       fmaxf(fmaxf(s2[0], s2[1]), fmaxf(s2[2], s2[3])));
    tmax = fmaxf(tmax, __shfl_xor(tmax, 16));
    tmax = fmaxf(tmax, __shfl_xor(tmax, 32));
    const float m_old = m_run;
    const float m_new = fmaxf(m_old, tmax);

    float p1[4], p2[4], tsum = 0.f;
#pragma unroll
    for (int r = 0; r < 4; ++r) {
      p1[r] = __expf(s1[r] - m_new);
      p2[r] = __expf(s2[r] - m_new);
      tsum += p1[r] + p2[r];
    }
    tsum += __shfl_xor(tsum, 16);
    tsum += __shfl_xor(tsum, 32);
    const float alpha = __expf(m_old - m_new);
    l_run = l_run * alpha + tsum;
    m_run = m_new;

    float dp = 0.f;
#pragma unroll
    for (int r = 0; r < 4; ++r) dp += p1[r] * kk1[r] + p2[r] * kk2[r];
    a128 = a128 * alpha + dp;

    if (__any(m_new > m_old)) {     // defer-rescale (alpha==1 for all -> skip)
      float ar[4];
#pragma unroll
      for (int r = 0; r < 4; ++r) ar[r] = __shfl(alpha, 4 * g + r);
#pragma unroll
      for (int dt = 0; dt < 8; ++dt)
#pragma unroll
        for (int r = 0; r < 4; ++r) accO[dt][r] *= ar[r];
    }

    // P fragment: slot e=r -> j=4g+r ; e=4+r -> j=16+4g+r (matches VT perm)
    f16x8 pa;
#pragma unroll
    for (int r = 0; r < 4; ++r) {
      pa[r]     = (_Float16)p1[r];
      pa[4 + r] = (_Float16)p2[r];
    }

    // ---- PV ----
#pragma unroll
    for (int dt = 0; dt < 8; ++dt)
      accO[dt] = __builtin_amdgcn_mfma_f32_16x16x32_f16(pa, vf[dt], accO[dt], 0, 0, 0);
  }

  // ---- merge 8 waves, write split partial ----
  a128 += __shfl_xor(a128, 16);
  a128 += __shfl_xor(a128, 32);
  if (lane < 16) mS[wid][lane] = m_run;
  __syncthreads();

  float M = mS[0][c];
#pragma unroll
  for (int w = 1; w < NWAVE; ++w) M = fmaxf(M, mS[w][c]);
  const float ew = __expf(m_run - M);
  if (lane < 16) { lS[wid][lane] = l_run * ew; aS[wid][lane] = a128 * ew; }

  float ewr[4];
#pragma unroll
  for (int r = 0; r < 4; ++r) ewr[r] = __shfl(ew, 4 * g + r);
#pragma unroll
  for (int dt = 0; dt < 8; ++dt)
#pragma unroll
    for (int r = 0; r < 4; ++r) accO[dt][r] *= ewr[r];

  if (wid < 4) {
#pragma unroll
    for (int dt = 0; dt < 8; ++dt)
#pragma unroll
      for (int r = 0; r < 4; ++r)
        OwS[wid][(4 * g + r) * 128 + dt * 16 + c] = accO[dt][r];
  }
  __syncthreads();
  if (wid >= 4) {
#pragma unroll
    for (int dt = 0; dt < 8; ++dt)
#pragma unroll
      for (int r = 0; r < 4; ++r)
        OwS[wid - 4][(4 * g + r) * 128 + dt * 16 + c] += accO[dt][r];
  }
  __syncthreads();

  {
    const int q = tid >> 5, s = tid & 31;
    f32x4 o = *reinterpret_cast<const f32x4*>(&OwS[0][q * 128 + 4 * s]);
#pragma unroll
    for (int i = 1; i < 4; ++i) {
      const f32x4 oi = *reinterpret_cast<const f32x4*>(&OwS[i][q * 128 + 4 * s]);
#pragma unroll
      for (int e = 0; e < 4; ++e) o[e] += oi[e];
    }
    float L = 0.f, A = 0.f, Mq = -INFINITY;
#pragma unroll
    for (int w = 0; w < NWAVE; ++w) {
      L += lS[w][q]; A += aS[w][q]; Mq = fmaxf(Mq, mS[w][q]);
    }
    float* dst = OP + ((size_t)(qg * NSPLIT + sp) * BM + q) * 128 + 4 * s;
    *reinterpret_cast<f32x4*>(dst) = o;
    if (s == 0) {
      float* mla = MLA + (size_t)(qg * NSPLIT + sp) * 48;
      mla[q] = Mq; mla[16 + q] = L; mla[32 + q] = A;
    }
  }
}

// ---------------- merge splits + double Lorentz normalization ----------------
__global__ __launch_bounds__(256) void merge_norm(
    const float* __restrict__ OP, const float* __restrict__ MLA,
    float* __restrict__ outg)
{
  const int qg  = blockIdx.x;
  const int rq  = threadIdx.x >> 4;   // 0..15
  const int seg = threadIdx.x & 15;   // 8 d-cols each

  const float* a0 = MLA + (size_t)(qg * NSPLIT + 0) * 48;
  const float* a1 = MLA + (size_t)(qg * NSPLIT + 1) * 48;
  const float m1 = a0[rq], l1 = a0[16 + rq], A1 = a0[32 + rq];
  const float m2 = a1[rq], l2 = a1[16 + rq], A2 = a1[32 + rq];
  const float M  = fmaxf(m1, m2);
  const float w1 = __expf(m1 - M), w2 = __expf(m2 - M);
  const float invL = 1.0f / (w1 * l1 + w2 * l2);

  const float* O1 = OP + ((size_t)(qg * NSPLIT + 0) * BM + rq) * 128 + 8 * seg;
  const float* O2 = OP + ((size_t)(qg * NSPLIT + 1) * BM + rq) * 128 + 8 * seg;
  float o[8];
#pragma unroll
  for (int i = 0; i < 8; ++i) o[i] = (w1 * O1[i] + w2 * O2[i]) * invL;
  const float A = (w1 * A1 + w2 * A2) * invL;

  float part = 0.f;
#pragma unroll
  for (int i = 0; i < 8; ++i) part += o[i] * o[i];
  if (seg == 0) part += -2.f * o[0] * o[0] + A * A;   // d0 negated, d128 added
  part += __shfl_xor(part, 1);
  part += __shfl_xor(part, 2);
  part += __shfl_xor(part, 4);
  part += __shfl_xor(part, 8);
  const float den1 = sqrtf(fmaxf(fabsf(part), 1e-8f));

  float y[8];
#pragma unroll
  for (int i = 0; i < 8; ++i) y[i] = o[i] / den1;
  const float yA = A / den1;

  float p2 = 0.f;
#pragma unroll
  for (int i = 0; i < 8; ++i) p2 += y[i] * y[i];
  if (seg == 0) p2 += -2.f * y[0] * y[0] + yA * yA;
  p2 += __shfl_xor(p2, 1);
  p2 += __shfl_xor(p2, 2);
  p2 += __shfl_xor(p2, 4);
  p2 += __shfl_xor(p2, 8);
  const float den2 = sqrtf(fmaxf(fabsf(p2), 1e-8f));

  float* orow = outg + (size_t)(qg * BM + rq) * DD;
#pragma unroll
  for (int i = 0; i < 8; ++i) orow[8 * seg + i] = y[i] / den2;
  if (seg == 0) orow[128] = yA / den2;
}

extern "C" void kernel_launch(void* const* d_in, const int* in_sizes, int n_in,
                              void* d_out, int out_size, void* d_ws, size_t ws_size,
                              hipStream_t stream) {
  const float* Qg = (const float*)d_in[0];
  const float* Kg = (const float*)d_in[1];
  const float* sc = (const float*)d_in[2];
  const float* bs = (const float*)d_in[3];
  float* out = (float*)d_out;

  char* ws = (char*)d_ws;
  short* Kh   = (short*)(ws + WS_KH);
  short* VT   = (short*)(ws + WS_VT);
  float* K128 = (float*)(ws + WS_K128);
  float* OP   = (float*)(ws + WS_OP);
  float* MLA  = (float*)(ws + WS_MLA);

  hipLaunchKernelGGL(prepass, dim3(NQ / 32), dim3(256), 0, stream, Kg, Kh, VT, K128);
  hipLaunchKernelGGL(attn_split, dim3(NQG * NSPLIT), dim3(NT), 0, stream,
                     Qg, Kh, VT, K128, sc, bs, OP, MLA);
  hipLaunchKernelGGL(merge_norm, dim3(NQG), dim3(256), 0, stream, OP, MLA, out);
}